// Round 9
// baseline (335.412 us; speedup 1.0000x reference)
//
#include <hip/hip_runtime.h>
#include <hip/hip_bf16.h>
#include <stdint.h>

#define Bn 4
#define Sn 2048
#define Dn 1024
#define Hn 16
#define HDn 64
#define Mn (Bn * Sn)  // 8192
#define PS 44         // P_lds row stride (elems): padded vs 32 to spread banks

typedef __attribute__((ext_vector_type(8))) __bf16 bf16x8;
typedef __attribute__((ext_vector_type(4))) __bf16 bf16x4;
typedef __attribute__((ext_vector_type(4))) float f32x4;

#if __has_builtin(__builtin_amdgcn_exp2f)
#define EXP2F(x) __builtin_amdgcn_exp2f(x)
#else
#define EXP2F(x) exp2f(x)
#endif

typedef __attribute__((address_space(1))) unsigned int as1_uint;
typedef __attribute__((address_space(3))) unsigned int as3_uint;

__device__ __forceinline__ void gld_lds16(const void* g, void* l) {
  __builtin_amdgcn_global_load_lds((const as1_uint*)g, (as3_uint*)l, 16, 0, 0);
}

// ------------- fused f32 -> bf16 conversion for all 7 arrays --------------
struct CvtArgs {
  const float* src[7];
};
__constant__ const size_t kGb[8] = {0,       1048576, 2097152, 3145728,
                                    3276800, 3407872, 3538944, 3670016};

__global__ __launch_bounds__(256) void cvt_all(CvtArgs a, __bf16* __restrict__ dst) {
  size_t i = (size_t)blockIdx.x * 256 + threadIdx.x;
  if (i >= 3670016) return;
  int s = 0;
#pragma unroll
  for (int k = 1; k < 7; k++) s += (i >= kGb[k]) ? 1 : 0;
  const float4* sp = (const float4*)a.src[s] + 2 * (i - kGb[s]);
  float4 x = sp[0], y = sp[1];
  bf16x8 o;
  o[0] = (__bf16)x.x; o[1] = (__bf16)x.y; o[2] = (__bf16)x.z; o[3] = (__bf16)x.w;
  o[4] = (__bf16)y.x; o[5] = (__bf16)y.y; o[6] = (__bf16)y.z; o[7] = (__bf16)y.w;
  *(bf16x8*)(dst + 8 * i) = o;
}

// ------------- 128x128 tile GEMM, C = A @ W^T (+bias)*scale --------------
// MODE 0: bf16 row-major out. MODE 1: f32 row-major out.
// MODE 2: bf16 transposed-per-head out Vt[b][h][c][s] (for attention V).
template <int MODE>
__device__ __forceinline__ void gemm128_body(const __bf16* __restrict__ A,
                                             const __bf16* __restrict__ Bw,
                                             const float* __restrict__ bias,
                                             void* __restrict__ Cout, int m0, int n0,
                                             float scale) {
  __shared__ __align__(16) __bf16 lA[128 * 32];
  __shared__ __align__(16) __bf16 lB[128 * 32];
  const int tid = threadIdx.x;
  const int wave = tid >> 6, lane = tid & 63, quad = lane >> 4, l15 = lane & 15;
  const int wm = wave >> 1, wn = wave & 1;
  f32x4 acc[4][4] = {};
  const char* Ab = (const char*)(A + (size_t)m0 * Dn);
  const char* Bb = (const char*)(Bw + (size_t)n0 * Dn);
  char* lAc = (char*)lA;
  char* lBc = (char*)lB;
  const int o0 = tid * 16, o1 = o0 + 4096;
  const int r0 = o0 >> 6, c0 = o0 & 63;
  const int r1 = o1 >> 6, c1 = o1 & 63;

  for (int k0 = 0; k0 < Dn; k0 += 32) {
    __syncthreads();
    gld_lds16(Ab + (size_t)r0 * 2048 + k0 * 2 + c0, lAc + o0);
    gld_lds16(Ab + (size_t)r1 * 2048 + k0 * 2 + c1, lAc + o1);
    gld_lds16(Bb + (size_t)r0 * 2048 + k0 * 2 + c0, lBc + o0);
    gld_lds16(Bb + (size_t)r1 * 2048 + k0 * 2 + c1, lBc + o1);
    __syncthreads();
    bf16x8 af[4], bfv[4];
#pragma unroll
    for (int i = 0; i < 4; i++)
      af[i] = *(const bf16x8*)(lA + (wm * 64 + i * 16 + l15) * 32 + quad * 8);
#pragma unroll
    for (int t = 0; t < 4; t++)
      bfv[t] = *(const bf16x8*)(lB + (wn * 64 + t * 16 + l15) * 32 + quad * 8);
#pragma unroll
    for (int i = 0; i < 4; i++)
#pragma unroll
      for (int t = 0; t < 4; t++)
        acc[i][t] = __builtin_amdgcn_mfma_f32_16x16x32_bf16(af[i], bfv[t], acc[i][t], 0, 0, 0);
  }
  // epilogue: C/D layout col=lane&15, row=quad*4+reg (m89-verified)
#pragma unroll
  for (int i = 0; i < 4; i++) {
    const int rowb = m0 + wm * 64 + i * 16 + quad * 4;
#pragma unroll
    for (int t = 0; t < 4; t++) {
      const int col = n0 + wn * 64 + t * 16 + l15;
      const float bb = bias[col];
      if (MODE == 2) {
        // Vt[b][h][c][s]: 4 consecutive s per lane -> one 8B store
        const int b = rowb >> 11, s = rowb & 2047;
        const int h = col >> 6, c = col & 63;
        bf16x4 pk;
#pragma unroll
        for (int r = 0; r < 4; r++) pk[r] = (__bf16)(acc[i][t][r] + bb);
        *(bf16x4*)((__bf16*)Cout + (((size_t)(b * Hn + h) * HDn + c) * Sn + s)) = pk;
      } else {
#pragma unroll
        for (int r = 0; r < 4; r++) {
          float v = (acc[i][t][r] + bb) * scale;
          if (MODE == 1)
            ((float*)Cout)[(size_t)(rowb + r) * Dn + col] = v;
          else
            ((__bf16*)Cout)[(size_t)(rowb + r) * Dn + col] = (__bf16)v;
        }
      }
    }
  }
}

// R7: XCD-aware chunked swizzle on the GEMM grids (kept; R7 measured win).
__global__ __launch_bounds__(256, 3) void qkv_gemm(
    const __bf16* __restrict__ X, const __bf16* __restrict__ W,
    const float* __restrict__ bq, const float* __restrict__ bk,
    const float* __restrict__ bv, __bf16* __restrict__ out) {
  const int lin = blockIdx.x + (blockIdx.y << 3) + (blockIdx.z << 9);
  const int wg = (lin & 7) * 192 + (lin >> 3);
  const int z = wg >> 9, rem = wg & 511;
  const int m0 = (rem >> 3) * 128, n0 = (rem & 7) * 128;
  if (z == 0) {
    // fold softmax scale (1/8)*log2(e) into Q so scores are in exp2 domain
    gemm128_body<0>(X, W, bq, out, m0, n0, 0.18033688011112042f);
  } else if (z == 1) {
    gemm128_body<0>(X + (size_t)Mn * Dn, W + (size_t)Dn * Dn, bk,
                    out + (size_t)Mn * Dn, m0, n0, 1.0f);
  } else {
    gemm128_body<2>(X + 2 * (size_t)Mn * Dn, W + 2 * (size_t)Dn * Dn, bv,
                    out + 2 * (size_t)Mn * Dn, m0, n0, 1.0f);
  }
}

__global__ __launch_bounds__(256, 3) void out_gemm(const __bf16* __restrict__ A,
                                                   const __bf16* __restrict__ W,
                                                   const float* __restrict__ bo,
                                                   float* __restrict__ out) {
  const int lin = blockIdx.x + (blockIdx.y << 3);
  const int wg = (lin & 7) * 64 + (lin >> 3);
  const int m0 = (wg >> 3) * 128, n0 = (wg & 7) * 128;
  gemm128_body<1>(A, W, bo, out, m0, n0, 1.0f);
}

// ---------------- flash attention, one wave = 64 q-rows -------------------
// R10 = R9 (LDS-staged K/V, 87.8us) + in-block key-split for 4 waves/SIMD.
// R9 post-mortem: staging fixed the TA bound (MfmaUtil 20->31) but the grid
// (512 blocks = 2 blocks/CU) caps occupancy at 2 waves/SIMD while the body
// now needs only 96 VGPR -- the register cap that killed R4's key-split is
// GONE. So: 512-thread blocks, 8 waves: waves 0-3 = 4 q-subtiles x keys
// [0,1024), waves 4-7 = same q x keys [1024,2048). Per-wave tile stays 64
// q-rows (R6 lesson). Per-half double-buffered K/V tiles; LDS total 77824B
// -> 2 blocks/CU = 155.6KB <= 160KB = 16 waves/CU = 4/SIMD.
// Max-free exp2 partials additive -> R4-verified LDS merge epilogue,
// overlaid on dead kbuf/vbuf. launch_bounds(512,2) caps at 256 regs (no
// forced spill). Staging bytes/FETCH/FLOPs unchanged.
__global__ __launch_bounds__(512, 2) void flash_attn(const __bf16* __restrict__ Q,
                                                     const __bf16* __restrict__ K,
                                                     const __bf16* __restrict__ Vt,
                                                     __bf16* __restrict__ Aout) {
  __shared__ __align__(16) __bf16 plds[8][64 * PS];     // 45056 B
  __shared__ __align__(16) __bf16 kbuf[2][2][32 * 64];  // [half][dbuf] 16 KB
  __shared__ __align__(16) __bf16 vbuf[2][2][32 * 64];  // [half][dbuf] 16 KB
  const int tid = threadIdx.x;
  const int wave = tid >> 6, lane = tid & 63, quad = lane >> 4, l15 = lane & 15;
  const int qw = wave & 3, half = wave >> 2;
  // XCD swizzle: 512 blocks, XCD (lin&7) owns wg [(lin&7)*64, +64) = 8
  // consecutive bh -> 4MB K/V working set resident in its private L2.
  const int lin = blockIdx.x + (blockIdx.y << 3);  // gridDim.x == 8
  const int wg = (lin & 7) * 64 + (lin >> 3);
  const int bh = wg >> 3, qt = wg & 7;
  const int b = bh >> 4, h = bh & 15;
  const int q0 = qt * 256 + qw * 64;
  const __bf16* Qb = Q + ((size_t)b * Sn) * Dn + h * HDn;
  const char* Kbase = (const char*)(K + ((size_t)b * Sn) * Dn + h * HDn);
  const char* Vbase = (const char*)(Vt + (size_t)(b * Hn + h) * HDn * Sn);
  __bf16* myP = &plds[wave][0];

  // staging roles: thread tid stages 16B of K and 16B of V for ITS half
  // (tid>>8 == half). st in [0,256): K LDS row=st>>3, stored block st&7
  // holds logical block j=(st&7)^(row&7) -> swizzled source col.
  // V tile row r: [c=r s0..31 | c=r+32 s0..31]; logical block j: half=j>>2,
  // squad=j&3 -> source (c=r+32*vhalf, s=vsq*8).
  const int st = tid & 255;
  const int srow = st >> 3;  // 0..31
  const int jsrc = (st & 7) ^ (srow & 7);
  const int vhalf = jsrc >> 2, vsq = jsrc & 3;
  const size_t ksrc = (size_t)(half * (Sn / 2) + srow) * (Dn * 2) + jsrc * 16;
  const size_t vsrc =
      (size_t)(srow + 32 * vhalf) * (Sn * 2) + (half * (Sn / 2) + vsq * 8) * 2;

#define STAGE(BUFI, KREL)                                                       \
  {                                                                             \
    gld_lds16(Kbase + (size_t)(KREL) * (Dn * 2) + ksrc,                         \
              (char*)&kbuf[half][BUFI][0] + st * 16);                           \
    gld_lds16(Vbase + (size_t)(KREL) * 2 + vsrc,                                \
              (char*)&vbuf[half][BUFI][0] + st * 16);                           \
  }

  // resident Q fragments, used as MFMA *B*-operand: B[k=d][n=q]
  bf16x8 qf[4][2];
#pragma unroll
  for (int iq = 0; iq < 4; iq++)
#pragma unroll
    for (int s = 0; s < 2; s++)
      qf[iq][s] = *(const bf16x8*)(Qb + (size_t)(q0 + iq * 16 + l15) * Dn + s * 32 + quad * 8);

  f32x4 O[4][4] = {};  // O^T accumulators: [mc][iq], col=q=l15, row=c=quad*4+r
  float li[4] = {};    // per-lane row-sum partials, lane l15 owns q=iq*16+l15

  STAGE(0, 0)
  __syncthreads();

#pragma unroll 2
  for (int kt = 0; kt < Sn / 64; kt++) {  // 32 ksteps of 32 keys per half
    const int cur = kt & 1, nxt = cur ^ 1;
    // stage kt+1 tiles (async; lands before the end-of-kstep barrier)
    if (kt < Sn / 64 - 1) STAGE(nxt, (kt + 1) * 32)
    // fragments from LDS (swizzled reads; 2-way conflicts = free)
    bf16x8 kf[2][2], vf[4];
#pragma unroll
    for (int tk = 0; tk < 2; tk++)
#pragma unroll
      for (int s = 0; s < 2; s++) {
        const int jp = (s * 4 + quad) ^ (l15 & 7);
        kf[tk][s] = *(const bf16x8*)((const char*)&kbuf[half][cur][0] +
                                     (tk * 16 + l15) * 128 + jp * 16);
      }
#pragma unroll
    for (int mc = 0; mc < 4; mc++) {
      const int jp = ((mc >> 1) * 4 + quad) ^ (l15 & 7);
      vf[mc] = *(const bf16x8*)((const char*)&vbuf[half][cur][0] +
                                ((mc & 1) * 16 + l15) * 128 + jp * 16);
    }
    // S^T = K · Q^T : D[m=key][n=q]
    f32x4 sa[2][4];
    __builtin_amdgcn_s_setprio(1);
#pragma unroll
    for (int tk = 0; tk < 2; tk++)
#pragma unroll
      for (int iq = 0; iq < 4; iq++) {
        f32x4 z = {0.f, 0.f, 0.f, 0.f};
        z = __builtin_amdgcn_mfma_f32_16x16x32_bf16(kf[tk][0], qf[iq][0], z, 0, 0, 0);
        z = __builtin_amdgcn_mfma_f32_16x16x32_bf16(kf[tk][1], qf[iq][1], z, 0, 0, 0);
        sa[tk][iq] = z;
      }
    __builtin_amdgcn_s_setprio(0);
    // P = exp2(S^T): lane has 4 consecutive keys at q=iq*16+l15 -> b64 store
#pragma unroll
    for (int tk = 0; tk < 2; tk++)
#pragma unroll
      for (int iq = 0; iq < 4; iq++) {
        bf16x4 pk;
#pragma unroll
        for (int r = 0; r < 4; r++) {
          float p = EXP2F(sa[tk][iq][r]);
          li[iq] += p;
          pk[r] = (__bf16)p;
        }
        *(bf16x4*)(myP + (iq * 16 + l15) * PS + tk * 16 + quad * 4) = pk;
      }
    // PV: O^T[c][q] += Vt-frag (A) x P-frag (B). B[k=key][n=q]: lane l15=q,
    // keys quad*8..+7 contiguous in P[q][key] -> two b64 reads.
    // Same-wave DS ops execute in order: no barrier needed (R1/R2-verified).
    __builtin_amdgcn_s_setprio(1);
#pragma unroll
    for (int iq = 0; iq < 4; iq++) {
      bf16x4 plo = *(const bf16x4*)(myP + (iq * 16 + l15) * PS + quad * 8);
      bf16x4 phi = *(const bf16x4*)(myP + (iq * 16 + l15) * PS + quad * 8 + 4);
      bf16x8 pf = __builtin_shufflevector(plo, phi, 0, 1, 2, 3, 4, 5, 6, 7);
#pragma unroll
      for (int mc = 0; mc < 4; mc++)
        O[mc][iq] = __builtin_amdgcn_mfma_f32_16x16x32_bf16(vf[mc], pf, O[mc][iq], 0, 0, 0);
    }
    __builtin_amdgcn_s_setprio(0);
    // barrier: staging(nxt) landed + all waves done reading cur
    __syncthreads();
  }
#undef STAGE

  // merge key-halves: upper waves ship unnormalized O^T (+li) through LDS
  // overlaid on the dead kbuf/vbuf (16KB / 4KB needed). Chunked per-mc;
  // lanes contiguous 16B -> conflict-free; branches wave-uniform. (R4-
  // verified pattern.) Main loop ended with a barrier, so buffers are free.
  float* om = (float*)&kbuf[0][0][0];   // [qw][iq][lane*4] : 4*4*256 f32
  float* lim = (float*)&vbuf[0][0][0];  // [qw][iq][lane]   : 4*4*64  f32
#pragma unroll
  for (int mc = 0; mc < 4; mc++) {
    if (half) {
#pragma unroll
      for (int iq = 0; iq < 4; iq++)
        *(f32x4*)&om[(qw * 4 + iq) * 256 + lane * 4] = O[mc][iq];
      if (mc == 0)
#pragma unroll
        for (int iq = 0; iq < 4; iq++) lim[(qw * 4 + iq) * 64 + lane] = li[iq];
    }
    __syncthreads();
    if (!half) {
#pragma unroll
      for (int iq = 0; iq < 4; iq++)
        O[mc][iq] += *(const f32x4*)&om[(qw * 4 + iq) * 256 + lane * 4];
      if (mc == 0)
#pragma unroll
        for (int iq = 0; iq < 4; iq++) li[iq] += lim[(qw * 4 + iq) * 64 + lane];
    }
    __syncthreads();
  }
  if (half) return;

  // normalize: full row-sum = reduce partials across quads (keys split by quad)
  float inv[4];
#pragma unroll
  for (int iq = 0; iq < 4; iq++) {
    float s = li[iq];
    s += __shfl_xor(s, 16);
    s += __shfl_xor(s, 32);
    inv[iq] = 1.0f / s;
  }
  // store O^T tiles: lane has 4 consecutive c at fixed q -> 8B packed stores
#pragma unroll
  for (int mc = 0; mc < 4; mc++)
#pragma unroll
    for (int iq = 0; iq < 4; iq++) {
      bf16x4 o;
#pragma unroll
      for (int r = 0; r < 4; r++) o[r] = (__bf16)(O[mc][iq][r] * inv[iq]);
      *(bf16x4*)(Aout + ((size_t)b * Sn + q0 + iq * 16 + l15) * Dn + h * HDn + mc * 16 +
                 quad * 4) = o;
    }
}

extern "C" void kernel_launch(void* const* d_in, const int* in_sizes, int n_in,
                              void* d_out, int out_size, void* d_ws, size_t ws_size,
                              hipStream_t stream) {
  const float* bq = (const float*)d_in[4];
  const float* bk = (const float*)d_in[6];
  const float* bv = (const float*)d_in[8];
  const float* bo = (const float*)d_in[10];

  const size_t MD = (size_t)Mn * Dn;  // 8,388,608
  const size_t DD = (size_t)Dn * Dn;  // 1,048,576
  // ws layout (bf16): X[3*MD] | W[4*DD] | QKV(Q,K,Vt)[3*MD] | Attn[MD]
  __bf16* Xbf  = (__bf16*)d_ws;
  __bf16* Wbf  = Xbf + 3 * MD;
  __bf16* QKV  = Wbf + 4 * DD;
  __bf16* Attn = QKV + 3 * MD;

  CvtArgs ca;
  ca.src[0] = (const float*)d_in[0];  // query
  ca.src[1] = (const float*)d_in[1];  // key
  ca.src[2] = (const float*)d_in[2];  // value
  ca.src[3] = (const float*)d_in[3];  // Wq
  ca.src[4] = (const float*)d_in[5];  // Wk
  ca.src[5] = (const float*)d_in[7];  // Wv
  ca.src[6] = (const float*)d_in[9];  // Wo
  cvt_all<<<14336, 256, 0, stream>>>(ca, Xbf);

  qkv_gemm<<<dim3(Dn / 128, Mn / 128, 3), 256, 0, stream>>>(Xbf, Wbf, bq, bk, bv, QKV);
  flash_attn<<<dim3(Sn / 256, Bn * Hn), 512, 0, stream>>>(QKV, QKV + MD, QKV + 2 * MD, Attn);
  out_gemm<<<dim3(Dn / 128, Mn / 128), 256, 0, stream>>>(Attn, Wbf + 3 * DD, bo, (float*)d_out);
}